// Round 7
// baseline (233.580 us; speedup 1.0000x reference)
//
#include <hip/hip_runtime.h>
#include <float.h>

// ---------------------------------------------------------------------------
// VQ layer forward, MI355X. B=4, L=2048 (8192 tokens), D=1024, VQ_DIM=64,
// K_CODES=8192, EMA_K=5.
// Round 7: distance work fused into one launch (role per block) so argmin and
// top5 waves co-schedule; 4 independent MFMA chains (dep 16->4); fragment-
// major swizzled bf16 layout (all fragment loads = contiguous 1KB/wave);
// register ping-pong prefetch of streaming fragments. Round-6 k_argmin was
// latency-bound: MfmaUtil 14.5, VALUBusy 20.7, occupancy 23.
// ---------------------------------------------------------------------------

typedef __attribute__((ext_vector_type(8)))  short bf16x8;   // 8 bf16 = 4 VGPR
typedef __attribute__((ext_vector_type(16))) float f32x16;   // MFMA 32x32 acc

__device__ __forceinline__ unsigned short f2bf(float x) {
  unsigned u = __float_as_uint(x);
  unsigned r = (u + 0x7fffu + ((u >> 16) & 1u)) >> 16;   // RNE
  return (unsigned short)r;
}
__device__ __forceinline__ float bf2f(unsigned short b) {
  return __uint_as_float(((unsigned)b) << 16);
}
// fragment-major layout: entity-block(32) x ks(4) x lh(2) x lane(32) x 8 elems
__device__ __forceinline__ size_t frag_off(int e, int ks, int lh) {
  return ((size_t)((((e >> 5) * 4 + ks) * 2 + lh) * 32 + (e & 31))) * 8;
}

// sorted-5 insert, plain strict < (ties keep existing = earlier/lower index)
__device__ __forceinline__ void tins5(float& d0, float& d1, float& d2,
                                      float& d3, float& d4, int& i0, int& i1,
                                      int& i2, int& i3, int& i4, float dv,
                                      int iv) {
  if (dv < d4) {
    d4 = dv; i4 = iv;
    if (d4 < d3) { float t = d3; d3 = d4; d4 = t; int u = i3; i3 = i4; i4 = u; }
    if (d3 < d2) { float t = d2; d2 = d3; d3 = t; int u = i2; i2 = i3; i3 = u; }
    if (d2 < d1) { float t = d1; d1 = d2; d2 = t; int u = i1; i1 = i2; i2 = u; }
    if (d1 < d0) { float t = d0; d0 = d1; d1 = t; int u = i0; i0 = i1; i1 = u; }
  }
}
// sorted-5 insert, lexicographic (d, idx) — for cross-lane/wave merges
__device__ __forceinline__ void lins5(float& d0, float& d1, float& d2,
                                      float& d3, float& d4, int& i0, int& i1,
                                      int& i2, int& i3, int& i4, float dv,
                                      int iv) {
  if (dv < d4 || (dv == d4 && iv < i4)) {
    d4 = dv; i4 = iv;
    if (d4 < d3 || (d4 == d3 && i4 < i3)) { float t = d3; d3 = d4; d4 = t; int u = i3; i3 = i4; i4 = u; }
    if (d3 < d2 || (d3 == d2 && i3 < i2)) { float t = d2; d2 = d3; d3 = t; int u = i2; i2 = i3; i3 = u; }
    if (d2 < d1 || (d2 == d1 && i2 < i1)) { float t = d1; d1 = d2; d2 = t; int u = i1; i1 = i2; i2 = u; }
    if (d1 < d0 || (d1 == d0 && i1 < i0)) { float t = d0; d0 = d1; d1 = t; int u = i0; i0 = i1; i1 = u; }
  }
}

// ---------------- Kernel 1: hp = normalize(h @ proj_w + b), + bf16 split ---
__global__ __launch_bounds__(256) void k_proj(
    const float* __restrict__ h, const float* __restrict__ w,
    const float* __restrict__ bias, float* __restrict__ hp_norm,
    float* __restrict__ h2, unsigned short* __restrict__ hpH,
    unsigned short* __restrict__ hpL) {
  __shared__ __align__(16) float hs[16 * 68];   // 16 tok x 64 k (pad 68)
  __shared__ __align__(16) float ws[64 * 64];   // 64 k x 64 dim
  const int tid = threadIdx.x;
  const int tb = blockIdx.x * 16;
  const int tok = tid >> 4;
  const int dimg = tid & 15;
  const float4* h4 = (const float4*)h;
  const float4* w4 = (const float4*)w;
  float4* ws4 = (float4*)ws;
  float4 acc = {0.f, 0.f, 0.f, 0.f};
  for (int ch = 0; ch < 16; ++ch) {
    __syncthreads();   // previous chunk's reads done
    *(float4*)&hs[tok * 68 + dimg * 4] = h4[(size_t)(tb + tok) * 256 + ch * 16 + dimg];
#pragma unroll
    for (int i = 0; i < 4; ++i) {
      int idx = tid + i * 256;
      int k = idx >> 4, dq = idx & 15;
      ws4[k * 16 + dq] = w4[(size_t)(ch * 64 + k) * 16 + dq];
    }
    __syncthreads();
#pragma unroll 8
    for (int k = 0; k < 64; ++k) {
      float hv = hs[tok * 68 + k];
      float4 wv = *(const float4*)&ws[k * 64 + dimg * 4];
      acc.x = fmaf(hv, wv.x, acc.x);
      acc.y = fmaf(hv, wv.y, acc.y);
      acc.z = fmaf(hv, wv.z, acc.z);
      acc.w = fmaf(hv, wv.w, acc.w);
    }
  }
  const float4 bv = ((const float4*)bias)[dimg];
  acc.x += bv.x; acc.y += bv.y; acc.z += bv.z; acc.w += bv.w;
  float sq = acc.x * acc.x + acc.y * acc.y + acc.z * acc.z + acc.w * acc.w;
#pragma unroll
  for (int o = 1; o <= 8; o <<= 1) sq += __shfl_xor(sq, o, 64);
  float nrm = sqrtf(sq);
  float4 vn;
  vn.x = acc.x / nrm; vn.y = acc.y / nrm; vn.z = acc.z / nrm; vn.w = acc.w / nrm;
  ((float4*)hp_norm)[(size_t)(tb + tok) * 16 + dimg] = vn;
  unsigned short hx = f2bf(vn.x), hy = f2bf(vn.y), hz = f2bf(vn.z), hw = f2bf(vn.w);
  uint2 hi_pack, lo_pack;
  hi_pack.x = (unsigned)hx | ((unsigned)hy << 16);
  hi_pack.y = (unsigned)hz | ((unsigned)hw << 16);
  lo_pack.x = (unsigned)f2bf(vn.x - bf2f(hx)) | ((unsigned)f2bf(vn.y - bf2f(hy)) << 16);
  lo_pack.y = (unsigned)f2bf(vn.z - bf2f(hz)) | ((unsigned)f2bf(vn.w - bf2f(hw)) << 16);
  // fragment-major: dims 4*dimg..4*dimg+3 -> ks=dimg>>2, lh=(dimg>>1)&1, half=dimg&1
  {
    int ks = dimg >> 2, lh = (dimg >> 1) & 1, half = dimg & 1;
    size_t off = frag_off(tb + tok, ks, lh) + half * 4;
    *(uint2*)(hpH + off) = hi_pack;
    *(uint2*)(hpL + off) = lo_pack;
  }
  float s2 = vn.x * vn.x + vn.y * vn.y + vn.z * vn.z + vn.w * vn.w;
#pragma unroll
  for (int o = 1; o <= 8; o <<= 1) s2 += __shfl_xor(s2, o, 64);
  if (dimg == 0) h2[tb + tok] = s2;
}

// ---------------- Kernel 2: E-normalize + initcount + wT transpose ---------
// grid 2096: [0,2048) enorm, [2048,2080) newcount=count, [2080,2096) wT.
__global__ __launch_bounds__(256) void k_enorm(
    const float* __restrict__ emb, float* __restrict__ E,
    float* __restrict__ e2, unsigned short* __restrict__ EH,
    unsigned short* __restrict__ EL,
    const float* __restrict__ cnt, float* __restrict__ ncnt,
    const float* __restrict__ wiv, unsigned short* __restrict__ wTH,
    unsigned short* __restrict__ wTL) {
  __shared__ float tile[64][65];
  const int b = blockIdx.x;
  const int tid = threadIdx.x;
  if (b >= 2080) {               // transpose proj_inv_w [64][1024] -> [n][k]
    const int n0 = (b - 2080) * 64;
    const float4* w4 = (const float4*)wiv;
#pragma unroll
    for (int i = 0; i < 4; ++i) {
      int idx = tid + i * 256;
      int k = idx >> 4, nq = idx & 15;
      float4 v = w4[k * 256 + (n0 >> 2) + nq];
      tile[nq * 4 + 0][k] = v.x;
      tile[nq * 4 + 1][k] = v.y;
      tile[nq * 4 + 2][k] = v.z;
      tile[nq * 4 + 3][k] = v.w;
    }
    __syncthreads();
    const int n = tid >> 2;
    const int k0 = (tid & 3) * 16;
#pragma unroll
    for (int j = 0; j < 16; j += 4) {
      int k = k0 + j;
      float x0 = tile[n][k], x1 = tile[n][k + 1], x2 = tile[n][k + 2],
            x3 = tile[n][k + 3];
      unsigned short h0 = f2bf(x0), h1 = f2bf(x1), h2_ = f2bf(x2), h3 = f2bf(x3);
      uint2 hp_, lp_;
      hp_.x = (unsigned)h0 | ((unsigned)h1 << 16);
      hp_.y = (unsigned)h2_ | ((unsigned)h3 << 16);
      lp_.x = (unsigned)f2bf(x0 - bf2f(h0)) | ((unsigned)f2bf(x1 - bf2f(h1)) << 16);
      lp_.y = (unsigned)f2bf(x2 - bf2f(h2_)) | ((unsigned)f2bf(x3 - bf2f(h3)) << 16);
      size_t off = frag_off(n0 + n, k >> 4, (k >> 3) & 1) + (k & 7);
      *(uint2*)(wTH + off) = hp_;
      *(uint2*)(wTL + off) = lp_;
    }
    return;
  }
  if (b >= 2048) {               // new_count = count
    int i = (b - 2048) * 256 + tid;
    ncnt[i] = cnt[i];
    return;
  }
  const int c = b * 4 + (tid >> 6);
  const int lane = tid & 63;
  float v = emb[(size_t)c * 64 + lane];
  float sq = v * v;
#pragma unroll
  for (int o = 32; o > 0; o >>= 1) sq += __shfl_xor(sq, o, 64);
  float vn = v / sqrtf(sq);
  E[(size_t)c * 64 + lane] = vn;
  unsigned short hb = f2bf(vn);
  size_t off = frag_off(c, lane >> 4, (lane >> 3) & 1) + (lane & 7);
  EH[off] = hb;
  EL[off] = f2bf(vn - bf2f(hb));
  float s2 = vn * vn;
#pragma unroll
  for (int o = 32; o > 0; o >>= 1) s2 += __shfl_xor(s2, o, 64);
  if (lane == 0) e2[c] = s2;
}

// ---------------- Kernel 3: fused distance (argmin | top5 per block) -------
// grid (256, 8): role = x&1 (0=argmin over codes, 1=top5 over tokens),
// tile = x>>1 (64 entities resident), y = strip of 1024 streamed entities.
__global__ __launch_bounds__(256, 2) void k_dist(
    const unsigned short* __restrict__ hpH, const unsigned short* __restrict__ hpL,
    const unsigned short* __restrict__ EH, const unsigned short* __restrict__ EL,
    const float* __restrict__ h2g, const float* __restrict__ e2g,
    const float* __restrict__ maskg,
    float* __restrict__ amin_d, int* __restrict__ amin_c,
    float* __restrict__ t5d, int* __restrict__ t5i) {
  __shared__ __align__(16) unsigned char smem[31744];
  const int role = blockIdx.x & 1;
  const int tile = blockIdx.x >> 1;
  const int tid = threadIdx.x;
  const int w = tid >> 6, lane = tid & 63;
  const int l31 = lane & 31, lh = lane >> 5;
  const int rowg = w >> 1, colg = w & 1;

  if (role == 0) {
    // ---------------- argmin over codes: 64 tokens resident ----------------
    float* mD = (float*)smem;            // [2][64]
    int* mC = (int*)(smem + 512);        // [2][64]
    const int tok_base = tile * 64;
    const int row_t = tok_base + rowg * 32 + l31;
    bf16x8 aH[4], aL[4];
#pragma unroll
    for (int ks = 0; ks < 4; ++ks) {
      aH[ks] = *(const bf16x8*)(hpH + frag_off(row_t, ks, lh));
      aL[ks] = *(const bf16x8*)(hpL + frag_off(row_t, ks, lh));
    }
    float h2r[16];
#pragma unroll
    for (int r = 0; r < 16; ++r) {
      int roff = (r & 3) + 8 * (r >> 2) + 4 * lh;
      h2r[r] = h2g[tok_base + rowg * 32 + roff];
    }
    float bd[16]; int bc[16];
#pragma unroll
    for (int r = 0; r < 16; ++r) { bd[r] = FLT_MAX; bc[r] = 0x7fffffff; }
    const int cstrip = blockIdx.y * 1024;
    bf16x8 bufH[2][4], bufL[2][4];
    float bufE[2];
    {
      const int c0 = cstrip + colg * 32 + l31;
#pragma unroll
      for (int ks = 0; ks < 4; ++ks) {
        bufH[0][ks] = *(const bf16x8*)(EH + frag_off(c0, ks, lh));
        bufL[0][ks] = *(const bf16x8*)(EL + frag_off(c0, ks, lh));
      }
      bufE[0] = e2g[c0];
    }
#pragma unroll
    for (int ch = 0; ch < 16; ++ch) {
      const int cur = ch & 1, nxt = cur ^ 1;
      const int cur_c = cstrip + ch * 64 + colg * 32 + l31;
      if (ch < 15) {
        const int nc = cur_c + 64;
#pragma unroll
        for (int ks = 0; ks < 4; ++ks) {
          bufH[nxt][ks] = *(const bf16x8*)(EH + frag_off(nc, ks, lh));
          bufL[nxt][ks] = *(const bf16x8*)(EL + frag_off(nc, ks, lh));
        }
        bufE[nxt] = e2g[nc];
      }
      f32x16 c0 = {}, c1 = {}, c2 = {}, c3 = {};
#pragma unroll
      for (int ks = 0; ks < 4; ++ks) {
        c0 = __builtin_amdgcn_mfma_f32_32x32x16_bf16(aL[ks], bufL[cur][ks], c0, 0, 0, 0);
        c1 = __builtin_amdgcn_mfma_f32_32x32x16_bf16(aL[ks], bufH[cur][ks], c1, 0, 0, 0);
        c2 = __builtin_amdgcn_mfma_f32_32x32x16_bf16(aH[ks], bufL[cur][ks], c2, 0, 0, 0);
        c3 = __builtin_amdgcn_mfma_f32_32x32x16_bf16(aH[ks], bufH[cur][ks], c3, 0, 0, 0);
      }
      const float e2c = bufE[cur];
#pragma unroll
      for (int r = 0; r < 16; ++r) {
        float dot = ((c0[r] + c1[r]) + c2[r]) + c3[r];
        float d = fmaf(-2.f, dot, h2r[r] + e2c);
        if (d < bd[r]) { bd[r] = d; bc[r] = cur_c; }   // codes ascend: strict <
      }
    }
#pragma unroll
    for (int r = 0; r < 16; ++r) {
#pragma unroll
      for (int o = 1; o <= 16; o <<= 1) {
        float od = __shfl_xor(bd[r], o, 64);
        int oc = __shfl_xor(bc[r], o, 64);
        if (od < bd[r] || (od == bd[r] && oc < bc[r])) { bd[r] = od; bc[r] = oc; }
      }
    }
    if (l31 == 0) {
#pragma unroll
      for (int r = 0; r < 16; ++r) {
        int roff = (r & 3) + 8 * (r >> 2) + 4 * lh;
        mD[colg * 64 + rowg * 32 + roff] = bd[r];
        mC[colg * 64 + rowg * 32 + roff] = bc[r];
      }
    }
    __syncthreads();
    if (tid < 64) {
      float d0 = mD[tid], d1 = mD[64 + tid];
      int c0 = mC[tid], c1 = mC[64 + tid];
      if (d1 < d0 || (d1 == d0 && c1 < c0)) { d0 = d1; c0 = c1; }
      int t = tok_base + tid;
      amin_d[(size_t)t * 8 + blockIdx.y] = d0;
      amin_c[(size_t)t * 8 + blockIdx.y] = c0;
    }
  } else {
    // ---------------- top5 tokens per code: 64 codes resident --------------
    float* Pm = (float*)smem;                         // [1024]
    float* Mm = (float*)(smem + 4096);                // [1024]
    float* bufD = (float*)(smem + 8192);              // [4][64][9]
    int* bufI = (int*)(smem + 17408);                 // [4][64][9]
    float* sD = (float*)(smem + 26624);               // [2][2][32][5]
    int* sI = (int*)(smem + 29184);                   // [2][2][32][5]
    const int code_base = tile * 64;
    const int col_c = code_base + colg * 32 + l31;
    const int tstrip = blockIdx.y * 1024;
#pragma unroll
    for (int i = 0; i < 4; ++i) {
      int t = tid + i * 256;
      float m = maskg[tstrip + t];
      Mm[t] = m;
      Pm[t] = fmaf(h2g[tstrip + t], m, 1.0e7f * (1.f - m));
    }
    bf16x8 bH[4], bL[4];
#pragma unroll
    for (int ks = 0; ks < 4; ++ks) {
      bH[ks] = *(const bf16x8*)(EH + frag_off(col_c, ks, lh));
      bL[ks] = *(const bf16x8*)(EL + frag_off(col_c, ks, lh));
    }
    const float e2c = e2g[col_c];
    float td0 = FLT_MAX, td1 = FLT_MAX, td2 = FLT_MAX, td3 = FLT_MAX, td4 = FLT_MAX;
    int ti0 = 0x7fffffff, ti1 = 0x7fffffff, ti2 = 0x7fffffff, ti3 = 0x7fffffff,
        ti4 = 0x7fffffff;
    int cnt = 0;
    float* myD = bufD + (w * 64 + lane) * 9;
    int* myI = bufI + (w * 64 + lane) * 9;
    auto drain = [&]() {
      int k = 0;
      while (__any(k < cnt)) {
        bool act = k < cnt;
        float dv = act ? myD[k] : FLT_MAX;
        int iv = act ? myI[k] : 0x7fffffff;
        tins5(td0, td1, td2, td3, td4, ti0, ti1, ti2, ti3, ti4, dv, iv);
        ++k;
      }
      cnt = 0;
    };
    bf16x8 bufAH[2][4], bufAL[2][4];
    {
      const int r0 = tstrip + rowg * 32 + l31;
#pragma unroll
      for (int ks = 0; ks < 4; ++ks) {
        bufAH[0][ks] = *(const bf16x8*)(hpH + frag_off(r0, ks, lh));
        bufAL[0][ks] = *(const bf16x8*)(hpL + frag_off(r0, ks, lh));
      }
    }
    __syncthreads();
#pragma unroll
    for (int ch = 0; ch < 16; ++ch) {
      const int cur = ch & 1, nxt = cur ^ 1;
      if (ch < 15) {
        const int nr = tstrip + (ch + 1) * 64 + rowg * 32 + l31;
#pragma unroll
        for (int ks = 0; ks < 4; ++ks) {
          bufAH[nxt][ks] = *(const bf16x8*)(hpH + frag_off(nr, ks, lh));
          bufAL[nxt][ks] = *(const bf16x8*)(hpL + frag_off(nr, ks, lh));
        }
      }
      f32x16 c0 = {}, c1 = {}, c2 = {}, c3 = {};
#pragma unroll
      for (int ks = 0; ks < 4; ++ks) {
        c0 = __builtin_amdgcn_mfma_f32_32x32x16_bf16(bufAL[cur][ks], bL[ks], c0, 0, 0, 0);
        c1 = __builtin_amdgcn_mfma_f32_32x32x16_bf16(bufAL[cur][ks], bH[ks], c1, 0, 0, 0);
        c2 = __builtin_amdgcn_mfma_f32_32x32x16_bf16(bufAH[cur][ks], bL[ks], c2, 0, 0, 0);
        c3 = __builtin_amdgcn_mfma_f32_32x32x16_bf16(bufAH[cur][ks], bH[ks], c3, 0, 0, 0);
      }
      const int rowb = ch * 64 + rowg * 32 + 4 * lh;   // strip-local token base
#pragma unroll
      for (int half = 0; half < 2; ++half) {
#pragma unroll
        for (int rq2 = 0; rq2 < 2; ++rq2) {
          const int rq = half * 2 + rq2;
          float4 pv = *(const float4*)&Pm[rowb + 8 * rq];
          float4 mv = *(const float4*)&Mm[rowb + 8 * rq];
          const int tok0 = tstrip + rowb + 8 * rq;
          float u, d;
          float dot;
          dot = ((c0[4 * rq + 0] + c1[4 * rq + 0]) + c2[4 * rq + 0]) + c3[4 * rq + 0];
          u = fmaf(-2.f, dot, e2c); d = fmaf(mv.x, u, pv.x);
          if (d < td4) { myD[cnt] = d; myI[cnt] = tok0 + 0; ++cnt; }
          dot = ((c0[4 * rq + 1] + c1[4 * rq + 1]) + c2[4 * rq + 1]) + c3[4 * rq + 1];
          u = fmaf(-2.f, dot, e2c); d = fmaf(mv.y, u, pv.y);
          if (d < td4) { myD[cnt] = d; myI[cnt] = tok0 + 1; ++cnt; }
          dot = ((c0[4 * rq + 2] + c1[4 * rq + 2]) + c2[4 * rq + 2]) + c3[4 * rq + 2];
          u = fmaf(-2.f, dot, e2c); d = fmaf(mv.z, u, pv.z);
          if (d < td4) { myD[cnt] = d; myI[cnt] = tok0 + 2; ++cnt; }
          dot = ((c0[4 * rq + 3] + c1[4 * rq + 3]) + c2[4 * rq + 3]) + c3[4 * rq + 3];
          u = fmaf(-2.f, dot, e2c); d = fmaf(mv.w, u, pv.w);
          if (d < td4) { myD[cnt] = d; myI[cnt] = tok0 + 3; ++cnt; }
        }
        drain();   // cap 8 respected: at most 8 candidates per half-chunk
      }
    }
    // merge lane <-> lane^32 (same code column, other row-half)
    {
      float od0 = __shfl_xor(td0, 32, 64), od1 = __shfl_xor(td1, 32, 64),
            od2 = __shfl_xor(td2, 32, 64), od3 = __shfl_xor(td3, 32, 64),
            od4 = __shfl_xor(td4, 32, 64);
      int oi0 = __shfl_xor(ti0, 32, 64), oi1 = __shfl_xor(ti1, 32, 64),
          oi2 = __shfl_xor(ti2, 32, 64), oi3 = __shfl_xor(ti3, 32, 64),
          oi4 = __shfl_xor(ti4, 32, 64);
      lins5(td0, td1, td2, td3, td4, ti0, ti1, ti2, ti3, ti4, od0, oi0);
      lins5(td0, td1, td2, td3, td4, ti0, ti1, ti2, ti3, ti4, od1, oi1);
      lins5(td0, td1, td2, td3, td4, ti0, ti1, ti2, ti3, ti4, od2, oi2);
      lins5(td0, td1, td2, td3, td4, ti0, ti1, ti2, ti3, ti4, od3, oi3);
      lins5(td0, td1, td2, td3, td4, ti0, ti1, ti2, ti3, ti4, od4, oi4);
    }
    if (lane < 32) {
      float* s = sD + (((colg * 2 + rowg) * 32) + l31) * 5;
      int* si = sI + (((colg * 2 + rowg) * 32) + l31) * 5;
      s[0] = td0; s[1] = td1; s[2] = td2; s[3] = td3; s[4] = td4;
      si[0] = ti0; si[1] = ti1; si[2] = ti2; si[3] = ti3; si[4] = ti4;
    }
    __syncthreads();
    if (tid < 64) {
      int cg = tid >> 5, cl = tid & 31;
      float* s0 = sD + ((cg * 2 + 0) * 32 + cl) * 5;
      int* s0i = sI + ((cg * 2 + 0) * 32 + cl) * 5;
      float* s1 = sD + ((cg * 2 + 1) * 32 + cl) * 5;
      int* s1i = sI + ((cg * 2 + 1) * 32 + cl) * 5;
      float rd0 = s0[0], rd1 = s0[1], rd2 = s0[2], rd3 = s0[3], rd4 = s0[4];
      int ri0 = s0i[0], ri1 = s0i[1], ri2 = s0i[2], ri3 = s0i[3], ri4 = s0i[4];
#pragma unroll
      for (int s = 0; s < 5; ++s)
        lins5(rd0, rd1, rd2, rd3, rd4, ri0, ri1, ri2, ri3, ri4, s1[s], s1i[s]);
      int code = code_base + cg * 32 + cl;
      size_t gb = (size_t)code * 40 + (size_t)blockIdx.y * 5;
      t5d[gb + 0] = rd0; t5i[gb + 0] = ri0;
      t5d[gb + 1] = rd1; t5i[gb + 1] = ri1;
      t5d[gb + 2] = rd2; t5i[gb + 2] = ri2;
      t5d[gb + 3] = rd3; t5i[gb + 3] = ri3;
      t5d[gb + 4] = rd4; t5i[gb + 4] = ri4;
    }
  }
}

// ---------------- Kernel 4: merge argmin, code, histogram, token loss ------
__global__ __launch_bounds__(256) void k_code(
    const float* __restrict__ amin_d, const int* __restrict__ amin_c,
    const float* __restrict__ hp, const float* __restrict__ E,
    const float* __restrict__ maskg,
    float* __restrict__ code_f, int* __restrict__ code_i,
    float* __restrict__ newcount, float* __restrict__ loss_tok) {
  const int wid = threadIdx.x >> 6;
  const int lane = threadIdx.x & 63;
  const int t = blockIdx.x * 4 + wid;
  float d = FLT_MAX;
  int c = 0x7fffffff;
  if (lane < 8) {
    d = amin_d[(size_t)t * 8 + lane];
    c = amin_c[(size_t)t * 8 + lane];
  }
#pragma unroll
  for (int o = 1; o <= 4; o <<= 1) {
    float od = __shfl_xor(d, o, 64);
    int oc = __shfl_xor(c, o, 64);
    if (od < d || (od == d && oc < c)) { d = od; c = oc; }
  }
  c = __shfl(c, 0, 64);
  if (maskg[t] == 0.f) c = 0;   // masked row: all dists 1e7 -> argmin = 0
  float a = hp[(size_t)t * 64 + lane];
  float e = E[(size_t)c * 64 + lane];
  float q = a + (e - a);
  float df = a - q;
  float ad = fabsf(df);
  float l = ad < 1.f ? 0.5f * df * df : ad - 0.5f;
#pragma unroll
  for (int o = 32; o > 0; o >>= 1) l += __shfl_xor(l, o, 64);
  if (lane == 0) {
    code_f[t] = (float)c;
    code_i[t] = c;
    loss_tok[t] = l;
    atomicAdd(&newcount[c], 1.0f);
  }
}

// ---------------- Kernel 5: q_out = E[code] @ proj_inv_w + b (MFMA) --------
__global__ __launch_bounds__(256, 2) void k_qout(
    const int* __restrict__ code_i,
    const unsigned short* __restrict__ EH, const unsigned short* __restrict__ EL,
    const unsigned short* __restrict__ wTH, const unsigned short* __restrict__ wTL,
    const float* __restrict__ bias, float* __restrict__ qout) {
  const int tid = threadIdx.x;
  const int w = tid >> 6, lane = tid & 63;
  const int l31 = lane & 31, lh = lane >> 5;
  const int rowg = w >> 1, colg = w & 1;
  const int tok_base = blockIdx.x * 64;
  const int col_base = blockIdx.y * 64;
  const int row_t = tok_base + rowg * 32 + l31;
  const int c = code_i[row_t];
  const int n = col_base + colg * 32 + l31;
  bf16x8 aH[4], aL[4], bH[4], bL[4];
#pragma unroll
  for (int ks = 0; ks < 4; ++ks) {
    aH[ks] = *(const bf16x8*)(EH + frag_off(c, ks, lh));
    aL[ks] = *(const bf16x8*)(EL + frag_off(c, ks, lh));
    bH[ks] = *(const bf16x8*)(wTH + frag_off(n, ks, lh));
    bL[ks] = *(const bf16x8*)(wTL + frag_off(n, ks, lh));
  }
  f32x16 c0 = {}, c1 = {}, c2 = {}, c3 = {};
#pragma unroll
  for (int ks = 0; ks < 4; ++ks) {
    c0 = __builtin_amdgcn_mfma_f32_32x32x16_bf16(aL[ks], bL[ks], c0, 0, 0, 0);
    c1 = __builtin_amdgcn_mfma_f32_32x32x16_bf16(aL[ks], bH[ks], c1, 0, 0, 0);
    c2 = __builtin_amdgcn_mfma_f32_32x32x16_bf16(aH[ks], bL[ks], c2, 0, 0, 0);
    c3 = __builtin_amdgcn_mfma_f32_32x32x16_bf16(aH[ks], bH[ks], c3, 0, 0, 0);
  }
  const float bc = bias[n];
#pragma unroll
  for (int r = 0; r < 16; ++r) {
    int row = rowg * 32 + (r & 3) + 8 * (r >> 2) + 4 * lh;
    float dot = ((c0[r] + c1[r]) + c2[r]) + c3[r];
    qout[(size_t)(tok_base + row) * 1024 + n] = dot + bc;
  }
}

// ---------------- Kernel 6: merge top5 + EMA update; block 2048 = vq_loss --
__global__ __launch_bounds__(256) void k_emb(
    const float* __restrict__ t5d, const int* __restrict__ t5i,
    const float* __restrict__ hp, const float* __restrict__ E,
    float* __restrict__ newemb,
    const float* __restrict__ loss_tok, const float* __restrict__ maskg,
    float* __restrict__ vq) {
  __shared__ float S[256], M[256];
  const int tid = threadIdx.x;
  if (blockIdx.x == 2048) {      // vq_loss reduction
    float s = 0.f, m = 0.f;
    const int base = tid * 32;
    for (int i = 0; i < 32; ++i) {
      float mm = maskg[base + i];
      s = fmaf(loss_tok[base + i], mm, s);
      m += mm;
    }
    S[tid] = s; M[tid] = m;
    __syncthreads();
    if (tid == 0) {
      float tot = 0.f;
      for (int b = 0; b < 4; ++b) {
        float sb = 0.f, mb = 0.f;
        for (int i = 0; i < 64; ++i) { sb += S[b * 64 + i]; mb += M[b * 64 + i]; }
        tot += sb / mb;
      }
      vq[0] = tot * 1.25f / 256.0f;
    }
    return;
  }
  const int wid = tid >> 6;
  const int lane = tid & 63;
  const int c = blockIdx.x * 4 + wid;
  float d = FLT_MAX;
  int idx = 0x7fffffff;
  if (lane < 40) {
    d = t5d[(size_t)c * 40 + lane];
    idx = t5i[(size_t)c * 40 + lane];
  }
  float seld[5]; int sel[5];
#pragma unroll
  for (int r = 0; r < 5; ++r) {
    float bd = d; int bi = idx;
#pragma unroll
    for (int o = 1; o <= 32; o <<= 1) {
      float od = __shfl_xor(bd, o, 64);
      int oi = __shfl_xor(bi, o, 64);
      if (od < bd || (od == bd && oi < bi)) { bd = od; bi = oi; }
    }
    seld[r] = bd; sel[r] = bi;
    if (idx == bi) d = FLT_MAX;   // token ids unique across strips
  }
  float m5 = fabsf(seld[0]);
#pragma unroll
  for (int r = 1; r < 5; ++r) m5 = fminf(m5, fabsf(seld[r]));
  float hf = 0.f;
#pragma unroll
  for (int r = 0; r < 5; ++r) hf += hp[(size_t)sel[r] * 64 + lane];
  hf = hf / 5.0f;
  float ev = E[(size_t)c * 64 + lane];
  float outv = (m5 > 0.1f) ? (ev * 0.995f + hf * (float)(1.0 - 0.995)) : ev;
  newemb[(size_t)c * 64 + lane] = outv;
}

// ---------------------------------------------------------------------------
extern "C" void kernel_launch(void* const* d_in, const int* in_sizes, int n_in,
                              void* d_out, int out_size, void* d_ws,
                              size_t ws_size, hipStream_t stream) {
  (void)in_sizes; (void)n_in; (void)out_size; (void)ws_size;
  const float* h          = (const float*)d_in[0];
  const float* mask       = (const float*)d_in[1];
  const float* proj_w     = (const float*)d_in[2];
  const float* proj_b     = (const float*)d_in[3];
  const float* proj_inv_w = (const float*)d_in[4];
  const float* proj_inv_b = (const float*)d_in[5];
  const float* emb        = (const float*)d_in[6];
  const float* count      = (const float*)d_in[7];

  float* out      = (float*)d_out;
  float* q_out    = out;                 // 8388608
  float* code_f   = out + 8388608;       // 8192
  float* vq       = out + 8396800;       // 1
  float* newemb   = out + 8396801;       // 524288
  float* newcount = out + 8921089;       // 8192

  float* ws = (float*)d_ws;
  float* hp_norm        = ws;                                  // 524288
  float* h2             = ws + 524288;                         // 8192
  float* E              = ws + 532480;                         // 524288
  float* e2             = ws + 1056768;                        // 8192
  unsigned short* hpH   = (unsigned short*)(ws + 1064960);     // 262144 f
  unsigned short* hpL   = (unsigned short*)(ws + 1327104);     // 262144 f
  unsigned short* EH    = (unsigned short*)(ws + 1589248);     // 262144 f
  unsigned short* EL    = (unsigned short*)(ws + 1851392);     // 262144 f
  unsigned short* wTH   = (unsigned short*)(ws + 2113536);     // 32768 f
  unsigned short* wTL   = (unsigned short*)(ws + 2146304);     // 32768 f
  float* amin_d         = ws + 2179072;                        // 65536 (8192*8)
  int*   amin_c         = (int*)(ws + 2244608);                // 65536
  int*   code_i         = (int*)(ws + 2310144);                // 8192
  float* t5d            = ws + 2318336;                        // 327680 (8192*40)
  int*   t5i            = (int*)(ws + 2646016);                // 327680
  float* loss_tok       = ws + 2973696;                        // 8192

  k_proj<<<512, 256, 0, stream>>>(h, proj_w, proj_b, hp_norm, h2, hpH, hpL);
  k_enorm<<<2096, 256, 0, stream>>>(emb, E, e2, EH, EL, count, newcount,
                                    proj_inv_w, wTH, wTL);
  k_dist<<<dim3(256, 8), 256, 0, stream>>>(hpH, hpL, EH, EL, h2, e2, mask,
                                           amin_d, amin_c, t5d, t5i);
  k_code<<<2048, 256, 0, stream>>>(amin_d, amin_c, hp_norm, E, mask,
                                   code_f, code_i, newcount, loss_tok);
  k_qout<<<dim3(128, 16), 256, 0, stream>>>(code_i, EH, EL, wTH, wTL,
                                            proj_inv_b, q_out);
  k_emb<<<2049, 256, 0, stream>>>(t5d, t5i, hp_norm, E, newemb,
                                  loss_tok, mask, vq);
}